// Round 1
// baseline (670.614 us; speedup 1.0000x reference)
//
#include <hip/hip_runtime.h>
#include <hip/hip_bf16.h>

typedef __attribute__((ext_vector_type(8))) short s16x8;
typedef __attribute__((ext_vector_type(4))) float f32x4;

static __device__ __forceinline__ unsigned short f2bf(float f) {
    // round-to-nearest-even fp32 -> bf16 (inputs are finite; no NaN handling needed)
    unsigned int u = __float_as_uint(f);
    unsigned int r = (u + 0x7FFFu + ((u >> 16) & 1u)) >> 16;
    return (unsigned short)r;
}

// ---- degree (by src) + histogram (by dst) ----
__global__ void k_deg_hist(const int* __restrict__ src, const int* __restrict__ dst,
                           int* __restrict__ degi, int* __restrict__ cnt, int E) {
    int e = blockIdx.x * blockDim.x + threadIdx.x;
    if (e < E) {
        atomicAdd(&degi[src[e]], 1);
        atomicAdd(&cnt[dst[e]], 1);
    }
}

__global__ void k_dis(const int* __restrict__ degi, float* __restrict__ dis, int N) {
    int n = blockIdx.x * blockDim.x + threadIdx.x;
    if (n < N) {
        int d = degi[n];
        dis[n] = d > 0 ? rsqrtf((float)d) : 0.f;
    }
}

// ---- 3-kernel exclusive scan of cnt -> rowptr (and cursor copy) ----
__global__ void k_scan1(const int* __restrict__ cnt, int* __restrict__ incl,
                        int* __restrict__ bsum, int N) {
    __shared__ int sm[1024];
    int t = threadIdx.x;
    int i = blockIdx.x * 1024 + t;
    sm[t] = (i < N) ? cnt[i] : 0;
    __syncthreads();
    for (int off = 1; off < 1024; off <<= 1) {
        int add = (t >= off) ? sm[t - off] : 0;
        __syncthreads();
        sm[t] += add;
        __syncthreads();
    }
    if (i < N) incl[i] = sm[t];
    if (t == 1023) bsum[blockIdx.x] = sm[1023];
}

__global__ void k_scan2(const int* __restrict__ bsum, int* __restrict__ boff,
                        int nb, int* __restrict__ rowptr, int N) {
    if (threadIdx.x == 0 && blockIdx.x == 0) {
        int run = 0;
        for (int b = 0; b < nb; ++b) { boff[b] = run; run += bsum[b]; }
        rowptr[N] = run;  // == E
    }
}

__global__ void k_scan3(const int* __restrict__ cnt, const int* __restrict__ boff,
                        int* __restrict__ rowptr, int* __restrict__ cursor, int N) {
    int i = blockIdx.x * 1024 + threadIdx.x;
    if (i < N) {
        int ex = rowptr[i] - cnt[i] + boff[blockIdx.x];  // inclusive -> exclusive
        rowptr[i] = ex;
        cursor[i] = ex;
    }
}

// ---- bucket edges by dst; precompute per-edge norm ----
__global__ void k_scatter(const int* __restrict__ src, const int* __restrict__ dst,
                          const float* __restrict__ dis, int* __restrict__ cursor,
                          int* __restrict__ srcs, float* __restrict__ nrm, int E) {
    int e = blockIdx.x * blockDim.x + threadIdx.x;
    if (e < E) {
        int s = src[e], d = dst[e];
        int p = atomicAdd(&cursor[d], 1);
        srcs[p] = s;
        nrm[p] = -dis[s] * dis[d];
    }
}

// ---- x -> bf16 copy (T_0 for the GEMM) ----
__global__ void k_xb(const float* __restrict__ x, unsigned short* __restrict__ tb0, int n4) {
    int i = blockIdx.x * blockDim.x + threadIdx.x;
    if (i < n4) {
        float4 v = ((const float4*)x)[i];
        ushort4 o;
        o.x = f2bf(v.x); o.y = f2bf(v.y); o.z = f2bf(v.z); o.w = f2bf(v.w);
        ((ushort4*)tb0)[i] = o;
    }
}

// ---- W [K][64][64] fp32 -> Wt [j][K*64 + ... ] bf16 transposed (A-operand friendly) ----
__global__ void k_wt(const float* __restrict__ W, unsigned short* __restrict__ wt,
                     int total, int KI) {
    int t = blockIdx.x * blockDim.x + threadIdx.x;
    if (t < total) {
        float v = W[t];
        int k = t >> 12;        // /4096
        int r = t & 4095;
        int i = r >> 6;
        int j = r & 63;
        wt[(size_t)j * KI + (k << 6) + i] = f2bf(v);
    }
}

// ---- one Chebyshev propagation: Tnew = scale*(L_hat @ Told) + beta*Tprev ----
// one wave per dst node, lane = feature; CSR gather, no atomics
__global__ void k_prop(const float* __restrict__ Told, const float* __restrict__ Tprev,
                       float* __restrict__ Tnew, unsigned short* __restrict__ Tbn,
                       const int* __restrict__ rowptr, const int* __restrict__ srcs,
                       const float* __restrict__ nrm, int N, float scale, float beta) {
    int gt = blockIdx.x * blockDim.x + threadIdx.x;
    int wid = gt >> 6;
    int lane = gt & 63;
    if (wid >= N) return;
    int rs = rowptr[wid], re = rowptr[wid + 1];
    float acc = 0.f;
    int e = rs;
    for (; e + 4 <= re; e += 4) {
        int s0 = srcs[e], s1 = srcs[e + 1], s2 = srcs[e + 2], s3 = srcs[e + 3];
        float w0 = nrm[e], w1 = nrm[e + 1], w2 = nrm[e + 2], w3 = nrm[e + 3];
        float v0 = Told[(size_t)s0 * 64 + lane];
        float v1 = Told[(size_t)s1 * 64 + lane];
        float v2 = Told[(size_t)s2 * 64 + lane];
        float v3 = Told[(size_t)s3 * 64 + lane];
        acc = fmaf(w0, v0, acc);
        acc = fmaf(w1, v1, acc);
        acc = fmaf(w2, v2, acc);
        acc = fmaf(w3, v3, acc);
    }
    for (; e < re; ++e)
        acc = fmaf(nrm[e], Told[(size_t)srcs[e] * 64 + lane], acc);
    float r = scale * acc;
    if (beta != 0.f) r = fmaf(beta, Tprev[(size_t)wid * 64 + lane], r);
    size_t idx = (size_t)wid * 64 + lane;
    Tnew[idx] = r;          // fp32 for the recursion
    Tbn[idx] = f2bf(r);     // bf16 for the output GEMM
}

// ---- out = relu( sum_k T_k @ W_k + bias )  via  D = W^T . T^T  (MFMA 16x16x32 bf16)
// wave w of block handles j-tile [w*16, w*16+16); A-frags (W^T) register-resident.
template <int KS>
__global__ __launch_bounds__(256) void k_gemm(const unsigned short* __restrict__ tb,
                                              const unsigned short* __restrict__ wt,
                                              const float* __restrict__ bias,
                                              float* __restrict__ out,
                                              int N, int NF) {
    int lane = threadIdx.x & 63;
    int w = threadIdx.x >> 6;       // 0..3 -> j-tile
    int l16 = lane & 15;
    int quad = lane >> 4;
    const int KI = KS * 32;         // 512 for K=8

    // A operand: A[m][k], m = lane&15 (= j within tile), k = quad*8 + 0..7
    s16x8 afr[KS];
    {
        const unsigned short* wrow = wt + (size_t)(w * 16 + l16) * KI + quad * 8;
#pragma unroll
        for (int ks = 0; ks < KS; ++ks)
            afr[ks] = *reinterpret_cast<const s16x8*>(wrow + ks * 32);
    }
    f32x4 bias4 = *reinterpret_cast<const f32x4*>(bias + w * 16 + quad * 4);

    int ntiles = N >> 4;
    for (int t = blockIdx.x; t < ntiles; t += gridDim.x) {
        // B operand: B[k][n], n = lane&15 (= node), k = quad*8 + 0..7
        const unsigned short* bbase = tb + (size_t)(t * 16 + l16) * 64 + quad * 8;
        f32x4 acc = {0.f, 0.f, 0.f, 0.f};
#pragma unroll
        for (int ks = 0; ks < KS; ++ks) {
            s16x8 bf = *reinterpret_cast<const s16x8*>(
                bbase + (size_t)(ks >> 1) * NF + (ks & 1) * 32);
            acc = __builtin_amdgcn_mfma_f32_16x16x32_bf16(afr[ks], bf, acc, 0, 0, 0);
        }
        // D: col = lane&15 (node), row = quad*4 + reg (j within tile)
        float* orow = out + (size_t)(t * 16 + l16) * 64 + w * 16 + quad * 4;
        f32x4 r;
#pragma unroll
        for (int q = 0; q < 4; ++q) {
            float v = acc[q] + bias4[q];
            r[q] = v > 0.f ? v : 0.f;
        }
        *reinterpret_cast<f32x4*>(orow) = r;
    }
}

extern "C" void kernel_launch(void* const* d_in, const int* in_sizes, int n_in,
                              void* d_out, int out_size, void* d_ws, size_t ws_size,
                              hipStream_t stream) {
    const float* x    = (const float*)d_in[0];
    const int*   eidx = (const int*)d_in[1];
    const float* W    = (const float*)d_in[2];
    const float* bias = (const float*)d_in[3];
    float* out = (float*)d_out;

    const int NF = in_sizes[0];       // N*64
    const int N  = NF / 64;
    const int E  = in_sizes[1] / 2;
    const int K  = in_sizes[2] / 4096;

    const int* src = eidx;
    const int* dst = eidx + E;

    // workspace layout (~190 MB)
    char* ws = (char*)d_ws;
    size_t off = 0;
    auto alloc = [&](size_t bytes) -> char* {
        char* p = ws + off;
        off = (off + bytes + 255) & ~(size_t)255;
        return p;
    };
    float* Tf[3];
    for (int i = 0; i < 3; ++i) Tf[i] = (float*)alloc((size_t)NF * 4);   // fp32 recursion (rotating)
    unsigned short* Tb = (unsigned short*)alloc((size_t)K * NF * 2);     // bf16 copies T_0..T_{K-1}
    unsigned short* Wt = (unsigned short*)alloc((size_t)64 * K * 64 * 2);
    int*   srcs   = (int*)alloc((size_t)E * 4);
    float* nrm    = (float*)alloc((size_t)E * 4);
    int*   rowptr = (int*)alloc((size_t)(N + 1) * 4);
    int*   cursor = (int*)alloc((size_t)N * 4);
    int*   degcnt = (int*)alloc((size_t)2 * N * 4);
    int*   degi = degcnt;
    int*   cnt  = degcnt + N;
    float* dis  = (float*)alloc((size_t)N * 4);
    int*   bsum = (int*)alloc(1024);
    int*   boff = (int*)alloc(1024);
    (void)ws_size; (void)n_in; (void)out_size;

    hipMemsetAsync(degcnt, 0, (size_t)2 * N * 4, stream);

    int eb = (E + 255) / 256;
    k_deg_hist<<<eb, 256, 0, stream>>>(src, dst, degi, cnt, E);
    k_dis<<<(N + 255) / 256, 256, 0, stream>>>(degi, dis, N);
    int nb = (N + 1023) / 1024;
    k_scan1<<<nb, 1024, 0, stream>>>(cnt, rowptr, bsum, N);
    k_scan2<<<1, 64, 0, stream>>>(bsum, boff, nb, rowptr, N);
    k_scan3<<<nb, 1024, 0, stream>>>(cnt, boff, rowptr, cursor, N);
    k_scatter<<<eb, 256, 0, stream>>>(src, dst, dis, cursor, srcs, nrm, E);
    k_xb<<<(NF / 4 + 255) / 256, 256, 0, stream>>>(x, Tb, NF / 4);
    k_wt<<<(K * 4096 + 255) / 256, 256, 0, stream>>>(W, Wt, K * 4096, K * 64);

    // Chebyshev recursion: T1 = L x; Tk = 2 L T_{k-1} - T_{k-2}
    const float* Tm1 = x;
    const float* Tm2 = x;  // unused when beta==0
    for (int p = 1; p < K; ++p) {
        float* Tn = Tf[(p - 1) % 3];
        float scale = (p == 1) ? 1.f : 2.f;
        float beta  = (p == 1) ? 0.f : -1.f;
        k_prop<<<(N * 64 + 255) / 256, 256, 0, stream>>>(
            Tm1, Tm2, Tn, Tb + (size_t)p * NF, rowptr, srcs, nrm, N, scale, beta);
        Tm2 = Tm1;
        Tm1 = Tn;
    }

    if (K == 8)      k_gemm<16><<<1024, 256, 0, stream>>>(Tb, Wt, bias, out, N, NF);
    else if (K == 4) k_gemm<8><<<1024, 256, 0, stream>>>(Tb, Wt, bias, out, N, NF);
    else if (K == 2) k_gemm<4><<<1024, 256, 0, stream>>>(Tb, Wt, bias, out, N, NF);
    else if (K == 1) k_gemm<2><<<1024, 256, 0, stream>>>(Tb, Wt, bias, out, N, NF);
}